// Round 13
// baseline (196.318 us; speedup 1.0000x reference)
//
#include <hip/hip_runtime.h>
#include <hip/hip_bf16.h>

#define N_ROWS 20000
#define KNN 32
#define DIN 128
#define DOUT 128

// ---- kernel 0: pack transposed/fused weight layout ----
// WTp float layout: [d4][j][i] where d = d4*4+i, j in [0,256)
//   j <  128 : channel j of XA (wh[j][d]) ; j >= 128 : channel j-128 of XB (wh[j-128][128+d])
__global__ __launch_bounds__(256) void pack_wt(const float* __restrict__ wh,
                                               float* __restrict__ WTp) {
    int tid = blockIdx.x * 256 + threadIdx.x;  // 0..32767
    int i  = tid & 3;
    int j  = (tid >> 2) & 255;
    int d4 = tid >> 10;
    int d  = d4 * 4 + i;
    float v = (j < 128) ? wh[j * 256 + d] : wh[(j - 128) * 256 + 128 + d];
    WTp[tid] = v;
}

// ---- kernel 1: XA16[n][o] = bf16(x[n]·wh[o,:128]) ; XBp[n][o] = x[n]·wh[o,128:] + bh[o]
// 16-row tiles (1250 blocks), 256 threads: tx = t&63 (channel), ty = t>>6, 4 rows/thread
__global__ __launch_bounds__(256) void gemm_xaxb(const float* __restrict__ x,
                                                 const float* __restrict__ WTp,
                                                 const float* __restrict__ bh,
                                                 __hip_bfloat16* __restrict__ XA16,
                                                 float* __restrict__ XBp) {
    __shared__ float xs[16][128];   // 8 KB
    const int t = threadIdx.x;
    const int row0 = blockIdx.x * 16;   // 1250*16 == 20000 exactly

    #pragma unroll
    for (int i = 0; i < 2; ++i) {
        int idx = t + i * 256;          // float4 slot in [0,512)
        int r = idx >> 5, c4 = idx & 31;
        ((float4*)xs[r])[c4] = ((const float4*)(x + (size_t)(row0 + r) * DIN))[c4];
    }
    __syncthreads();

    const int tx = t & 63;
    const int ty = t >> 6;
    const int r0 = ty * 4;
    float acc[4][4];
    #pragma unroll
    for (int r = 0; r < 4; ++r)
        #pragma unroll
        for (int c = 0; c < 4; ++c) acc[r][c] = 0.f;

    const float4* W4 = (const float4*)WTp;
    for (int d4 = 0; d4 < 32; ++d4) {
        float4 w0 = W4[d4 * 256 + tx];         // XA, channel tx
        float4 w1 = W4[d4 * 256 + 64 + tx];    // XA, channel tx+64
        float4 w2 = W4[d4 * 256 + 128 + tx];   // XB, channel tx
        float4 w3 = W4[d4 * 256 + 192 + tx];   // XB, channel tx+64
        #pragma unroll
        for (int r = 0; r < 4; ++r) {
            float4 xv = ((const float4*)xs[r0 + r])[d4];  // wave-uniform broadcast
            acc[r][0] += xv.x * w0.x + xv.y * w0.y + xv.z * w0.z + xv.w * w0.w;
            acc[r][1] += xv.x * w1.x + xv.y * w1.y + xv.z * w1.z + xv.w * w1.w;
            acc[r][2] += xv.x * w2.x + xv.y * w2.y + xv.z * w2.z + xv.w * w2.w;
            acc[r][3] += xv.x * w3.x + xv.y * w3.y + xv.z * w3.z + xv.w * w3.w;
        }
    }

    float bh0 = bh[tx], bh1 = bh[64 + tx];
    #pragma unroll
    for (int r = 0; r < 4; ++r) {
        size_t gr = row0 + r0 + r;
        XA16[gr * DOUT + tx]       = __float2bfloat16(acc[r][0]);
        XA16[gr * DOUT + 64 + tx]  = __float2bfloat16(acc[r][1]);
        XBp [gr * DOUT + tx]       = acc[r][2] + bh0;
        XBp [gr * DOUT + 64 + tx]  = acc[r][3] + bh1;
    }
}

// ---- kernel 2: 256 threads = 4 independent waves, wave w owns n = blockIdx*4+w.
// (R10's 64-thread blocks capped residency at ~16 wg/CU = 49% occupancy; 4 waves
// per block lifts the workgroup-slot limit.) Per wave: idx/d broadcast via
// readlane -> SGPR gather base; in-loop 3 DPP shfl_xor -> 8 pos partials/k in
// per-wave-private LDS (stride 9, conflict-free).
__global__ __launch_bounds__(256) void fused_main(const float* __restrict__ dists,
                                                  const int*  __restrict__ argm,
                                                  const float* __restrict__ w1d,
                                                  const float* __restrict__ b1d,
                                                  const float* __restrict__ w2d,
                                                  const float* __restrict__ b2d,
                                                  const float* __restrict__ wp,
                                                  const float* __restrict__ bp,
                                                  const __hip_bfloat16* __restrict__ XA16,
                                                  const float* __restrict__ XBp,
                                                  float* __restrict__ out_pos,
                                                  float* __restrict__ out_struct) {
    const int w    = threadIdx.x >> 6;           // wave id 0..3
    const int lane = threadIdx.x & 63;
    const int n    = blockIdx.x * 4 + w;

    __shared__ float pos_p[4][KNN][9];           // 4.5 KB, per-wave slice

    // ---- distance MLP: k = lane&31, sub = lane>>5 handles 64 channels; 1 shfl_xor(32)
    const int k = lane & 31, sub = lane >> 5;
    float s = dists[(size_t)n * KNN + k];
    float a = 0.f;
    {
        const float4* W1 = (const float4*)(w1d + sub * 64);
        const float4* B1 = (const float4*)(b1d + sub * 64);
        const float4* W2 = (const float4*)(w2d + sub * 64);
        #pragma unroll
        for (int o4 = 0; o4 < 16; ++o4) {
            float4 w1 = W1[o4], b1 = B1[o4], w2 = W2[o4];
            a += fmaxf(fmaf(s, w1.x, b1.x), 0.f) * w2.x;
            a += fmaxf(fmaf(s, w1.y, b1.y), 0.f) * w2.y;
            a += fmaxf(fmaf(s, w1.z, b1.z), 0.f) * w2.z;
            a += fmaxf(fmaf(s, w1.w, b1.w), 0.f) * w2.w;
        }
    }
    a += __shfl_xor(a, 32);
    const float dval = a + b2d[0];               // lanes k and k+32 both hold d_k
    const int   idxv = argm[(size_t)n * KNN + k];// lanes k and k+32 hold idx_k

    // per-lane channel pair c = {2*lane, 2*lane+1}
    const float2 base = *(const float2*)(XBp + (size_t)n * DOUT + lane * 2);
    const float2 wpv  = *(const float2*)(wp + lane * 2);

    const unsigned* xa32 = (const unsigned*)XA16;   // row = 64 uints = 128 bf16
    float s0 = 0.f, s1 = 0.f;
    #pragma unroll
    for (int kk = 0; kk < KNN; ++kk) {
        int   m  = __builtin_amdgcn_readlane(idxv, kk);   // SGPR, uniform
        float dk = __int_as_float(__builtin_amdgcn_readlane(__float_as_int(dval), kk));
        unsigned u = xa32[(size_t)m * 64 + lane];         // s[base] + lane*4
        float xa0 = __uint_as_float(u << 16);             // low bf16
        float xa1 = __uint_as_float(u & 0xFFFF0000u);     // high bf16
        float h0 = fmaxf(fmaf(dk, xa0, base.x), 0.f);
        float h1 = fmaxf(fmaf(dk, xa1, base.y), 0.f);
        s0 += h0; s1 += h1;
        float pv = fmaf(h1, wpv.y, h0 * wpv.x);
        pv += __shfl_xor(pv, 1);                          // DPP adds
        pv += __shfl_xor(pv, 2);
        pv += __shfl_xor(pv, 4);
        if ((lane & 7) == 0) pos_p[w][kk][lane >> 3] = pv; // 8 banks, conflict-free
    }
    *(float2*)(out_struct + (size_t)n * DOUT + lane * 2) =
        make_float2(s0 * (1.f / KNN), s1 * (1.f / KNN));
    __syncthreads();   // orders per-wave LDS writes -> reads (waves arrive together)

    if (lane < KNN) {
        const float* row = pos_p[w][lane];                // banks 9*lane+j: bijective
        float p = ((row[0] + row[1]) + (row[2] + row[3]))
                + ((row[4] + row[5]) + (row[6] + row[7]));
        out_pos[(size_t)n * KNN + lane] = p + bp[0];
    }
}

extern "C" void kernel_launch(void* const* d_in, const int* in_sizes, int n_in,
                              void* d_out, int out_size, void* d_ws, size_t ws_size,
                              hipStream_t stream) {
    const float* data_x = (const float*)d_in[0];
    const float* dists  = (const float*)d_in[1];
    const int*   argm   = (const int*)d_in[2];
    const float* w1d    = (const float*)d_in[3];
    const float* b1d    = (const float*)d_in[4];
    const float* w2d    = (const float*)d_in[5];
    const float* b2d    = (const float*)d_in[6];
    const float* wh     = (const float*)d_in[7];
    const float* bh     = (const float*)d_in[8];
    const float* wp     = (const float*)d_in[9];
    const float* bp     = (const float*)d_in[10];

    float* out_pos    = (float*)d_out;                       // [N,K]
    float* out_struct = out_pos + (size_t)N_ROWS * KNN;      // [N,DOUT]

    float*          XBp  = (float*)d_ws;                                  // [N,128] f32
    __hip_bfloat16* XA16 = (__hip_bfloat16*)(XBp + (size_t)N_ROWS * DOUT);// [N,128] bf16
    float*          WTp  = (float*)((char*)XA16 + (size_t)N_ROWS * DOUT * 2); // 32768 f32

    pack_wt<<<128, 256, 0, stream>>>(wh, WTp);
    gemm_xaxb<<<N_ROWS / 16, 256, 0, stream>>>(data_x, WTp, bh, XA16, XBp);
    fused_main<<<N_ROWS / 4, 256, 0, stream>>>(dists, argm, w1d, b1d, w2d, b2d,
                                               wp, bp, XA16, XBp, out_pos, out_struct);
}

// Round 16
// 150.231 us; speedup vs baseline: 1.3068x; 1.3068x over previous
//
#include <hip/hip_runtime.h>
#include <hip/hip_bf16.h>

#define N_ROWS 20000
#define KNN 32
#define DIN 128
#define DOUT 128

// ---- kernel 0: pack transposed/fused weight layout ----
// WTp float layout: [d4][j][i] where d = d4*4+i, j in [0,256)
//   j <  128 : channel j of XA (wh[j][d]) ; j >= 128 : channel j-128 of XB (wh[j-128][128+d])
__global__ __launch_bounds__(256) void pack_wt(const float* __restrict__ wh,
                                               float* __restrict__ WTp) {
    int tid = blockIdx.x * 256 + threadIdx.x;  // 0..32767
    int i  = tid & 3;
    int j  = (tid >> 2) & 255;
    int d4 = tid >> 10;
    int d  = d4 * 4 + i;
    float v = (j < 128) ? wh[j * 256 + d] : wh[(j - 128) * 256 + 128 + d];
    WTp[tid] = v;
}

// ---- kernel 1: XA16[n][o] = bf16(x[n]·wh[o,:128]) ; XBp[n][o] = x[n]·wh[o,128:] + bh[o]
// 16-row tiles (1250 blocks), 256 threads: tx = t&63 (channel), ty = t>>6, 4 rows/thread
__global__ __launch_bounds__(256) void gemm_xaxb(const float* __restrict__ x,
                                                 const float* __restrict__ WTp,
                                                 const float* __restrict__ bh,
                                                 __hip_bfloat16* __restrict__ XA16,
                                                 float* __restrict__ XBp) {
    __shared__ float xs[16][128];   // 8 KB
    const int t = threadIdx.x;
    const int row0 = blockIdx.x * 16;   // 1250*16 == 20000 exactly

    #pragma unroll
    for (int i = 0; i < 2; ++i) {
        int idx = t + i * 256;          // float4 slot in [0,512)
        int r = idx >> 5, c4 = idx & 31;
        ((float4*)xs[r])[c4] = ((const float4*)(x + (size_t)(row0 + r) * DIN))[c4];
    }
    __syncthreads();

    const int tx = t & 63;
    const int ty = t >> 6;
    const int r0 = ty * 4;
    float acc[4][4];
    #pragma unroll
    for (int r = 0; r < 4; ++r)
        #pragma unroll
        for (int c = 0; c < 4; ++c) acc[r][c] = 0.f;

    const float4* W4 = (const float4*)WTp;
    for (int d4 = 0; d4 < 32; ++d4) {
        float4 w0 = W4[d4 * 256 + tx];         // XA, channel tx
        float4 w1 = W4[d4 * 256 + 64 + tx];    // XA, channel tx+64
        float4 w2 = W4[d4 * 256 + 128 + tx];   // XB, channel tx
        float4 w3 = W4[d4 * 256 + 192 + tx];   // XB, channel tx+64
        #pragma unroll
        for (int r = 0; r < 4; ++r) {
            float4 xv = ((const float4*)xs[r0 + r])[d4];  // wave-uniform broadcast
            acc[r][0] += xv.x * w0.x + xv.y * w0.y + xv.z * w0.z + xv.w * w0.w;
            acc[r][1] += xv.x * w1.x + xv.y * w1.y + xv.z * w1.z + xv.w * w1.w;
            acc[r][2] += xv.x * w2.x + xv.y * w2.y + xv.z * w2.z + xv.w * w2.w;
            acc[r][3] += xv.x * w3.x + xv.y * w3.y + xv.z * w3.z + xv.w * w3.w;
        }
    }

    float bh0 = bh[tx], bh1 = bh[64 + tx];
    #pragma unroll
    for (int r = 0; r < 4; ++r) {
        size_t gr = row0 + r0 + r;
        XA16[gr * DOUT + tx]       = __float2bfloat16(acc[r][0]);
        XA16[gr * DOUT + 64 + tx]  = __float2bfloat16(acc[r][1]);
        XBp [gr * DOUT + tx]       = acc[r][2] + bh0;
        XBp [gr * DOUT + 64 + tx]  = acc[r][3] + bh1;
    }
}

// ---- kernel 2: 4 independent waves/block (no barriers), wave owns one n.
// Lane L: channels c0=(L&15)*8 (one dwordx4 = 16B of the bf16 row);
// lane group g=L>>4 owns rows g*8..g*8+7 -> 8 x global_load_dwordx4 gathers
// (1KB/wave-instr). In-loop: FMA only + 1 ds_write (pos partial). No shfl,
// no readlane, no barrier in the loop.
__global__ __launch_bounds__(256) void fused_main(const float* __restrict__ dists,
                                                  const int*  __restrict__ argm,
                                                  const float* __restrict__ w1d,
                                                  const float* __restrict__ b1d,
                                                  const float* __restrict__ w2d,
                                                  const float* __restrict__ b2d,
                                                  const float* __restrict__ wp,
                                                  const float* __restrict__ bp,
                                                  const __hip_bfloat16* __restrict__ XA16,
                                                  const float* __restrict__ XBp,
                                                  float* __restrict__ out_pos,
                                                  float* __restrict__ out_struct) {
    const int w    = threadIdx.x >> 6;           // wave id 0..3
    const int lane = threadIdx.x & 63;
    const int n    = blockIdx.x * 4 + w;

    __shared__ int   m_lds[4][KNN];              // per-wave slices; no cross-wave use
    __shared__ float d_lds[4][KNN];
    __shared__ float pos_p[4][KNN][17];          // stride 17: conflict-free epi read

    // ---- distance MLP: k = lane&31, sub = lane>>5 (64 channels each);
    // 4 independent partial accumulators shorten the dependent FMA chain.
    {
        const int k = lane & 31, sub = lane >> 5;
        float s = dists[(size_t)n * KNN + k];
        const float4* W1 = (const float4*)(w1d + sub * 64);
        const float4* B1 = (const float4*)(b1d + sub * 64);
        const float4* W2 = (const float4*)(w2d + sub * 64);
        float acc[4] = {0.f, 0.f, 0.f, 0.f};
        #pragma unroll
        for (int o4 = 0; o4 < 16; ++o4) {
            float4 w1 = W1[o4], b1 = B1[o4], w2 = W2[o4];
            float t = fmaxf(fmaf(s, w1.x, b1.x), 0.f) * w2.x;
            t = fmaf(fmaxf(fmaf(s, w1.y, b1.y), 0.f), w2.y, t);
            t = fmaf(fmaxf(fmaf(s, w1.z, b1.z), 0.f), w2.z, t);
            t = fmaf(fmaxf(fmaf(s, w1.w, b1.w), 0.f), w2.w, t);
            acc[o4 & 3] += t;
        }
        float a = (acc[0] + acc[1]) + (acc[2] + acc[3]);
        a += __shfl_xor(a, 32);
        if (lane < KNN) {
            m_lds[w][lane] = argm[(size_t)n * KNN + lane];
            d_lds[w][lane] = a + b2d[0];
        }
        // same-wave LDS RAW below: compiler orders via lgkmcnt; no barrier needed
    }

    const int g  = lane >> 4;          // row group: rows g*8..g*8+7
    const int c4 = lane & 15;          // dwordx4 slot = channels c4*8..c4*8+7
    const int c0 = c4 * 8;

    // per-lane channel constants (8 floats each)
    float4 baseA = ((const float4*)(XBp + (size_t)n * DOUT + c0))[0];
    float4 baseB = ((const float4*)(XBp + (size_t)n * DOUT + c0))[1];
    float4 wpA   = ((const float4*)(wp + c0))[0];
    float4 wpB   = ((const float4*)(wp + c0))[1];

    // preload this group's 8 row indices + d values (broadcast ds_reads)
    int   mj[8];
    float dj[8];
    #pragma unroll
    for (int kk = 0; kk < 8; ++kk) {
        mj[kk] = m_lds[w][g * 8 + kk];
        dj[kk] = d_lds[w][g * 8 + kk];
    }

    const uint4* xa16v = (const uint4*)XA16;     // row = 16 uint4s
    float s0=0.f,s1=0.f,s2=0.f,s3=0.f,s4=0.f,s5=0.f,s6=0.f,s7=0.f;

    #pragma unroll
    for (int kk = 0; kk < 8; ++kk) {
        uint4 u = xa16v[(size_t)mj[kk] * 16 + c4];   // 16B/lane, 4 rows/instr
        float dk = dj[kk];
        float pv;
        {
            float x0 = __uint_as_float(u.x << 16);
            float x1 = __uint_as_float(u.x & 0xFFFF0000u);
            float h0 = fmaxf(fmaf(dk, x0, baseA.x), 0.f);
            float h1 = fmaxf(fmaf(dk, x1, baseA.y), 0.f);
            s0 += h0; s1 += h1;
            pv = fmaf(h1, wpA.y, h0 * wpA.x);
        }
        {
            float x0 = __uint_as_float(u.y << 16);
            float x1 = __uint_as_float(u.y & 0xFFFF0000u);
            float h0 = fmaxf(fmaf(dk, x0, baseA.z), 0.f);
            float h1 = fmaxf(fmaf(dk, x1, baseA.w), 0.f);
            s2 += h0; s3 += h1;
            pv = fmaf(h0, wpA.z, pv); pv = fmaf(h1, wpA.w, pv);
        }
        {
            float x0 = __uint_as_float(u.z << 16);
            float x1 = __uint_as_float(u.z & 0xFFFF0000u);
            float h0 = fmaxf(fmaf(dk, x0, baseB.x), 0.f);
            float h1 = fmaxf(fmaf(dk, x1, baseB.y), 0.f);
            s4 += h0; s5 += h1;
            pv = fmaf(h0, wpB.x, pv); pv = fmaf(h1, wpB.y, pv);
        }
        {
            float x0 = __uint_as_float(u.w << 16);
            float x1 = __uint_as_float(u.w & 0xFFFF0000u);
            float h0 = fmaxf(fmaf(dk, x0, baseB.z), 0.f);
            float h1 = fmaxf(fmaf(dk, x1, baseB.w), 0.f);
            s6 += h0; s7 += h1;
            pv = fmaf(h0, wpB.z, pv); pv = fmaf(h1, wpB.w, pv);
        }
        pos_p[w][g * 8 + kk][c4] = pv;           // <=2-way bank alias (free)
    }

    // structure reduce: combine the 4 row-groups (lanes L, L^16, L^32, L^48)
    #pragma unroll
    for (int st = 16; st <= 32; st <<= 1) {
        s0 += __shfl_xor(s0, st); s1 += __shfl_xor(s1, st);
        s2 += __shfl_xor(s2, st); s3 += __shfl_xor(s3, st);
        s4 += __shfl_xor(s4, st); s5 += __shfl_xor(s5, st);
        s6 += __shfl_xor(s6, st); s7 += __shfl_xor(s7, st);
    }
    if (lane < 16) {
        float* o = out_struct + (size_t)n * DOUT + c0;
        const float inv = 1.f / KNN;
        ((float4*)o)[0] = make_float4(s0*inv, s1*inv, s2*inv, s3*inv);
        ((float4*)o)[1] = make_float4(s4*inv, s5*inv, s6*inv, s7*inv);
    }

    // position epilogue: lane k<32 sums its row's 16 partials (stride 17 -> conflict-free)
    if (lane < KNN) {
        const float* row = pos_p[w][lane];
        float p = 0.f;
        #pragma unroll
        for (int j = 0; j < 16; ++j) p += row[j];
        out_pos[(size_t)n * KNN + lane] = p + bp[0];
    }
}

extern "C" void kernel_launch(void* const* d_in, const int* in_sizes, int n_in,
                              void* d_out, int out_size, void* d_ws, size_t ws_size,
                              hipStream_t stream) {
    const float* data_x = (const float*)d_in[0];
    const float* dists  = (const float*)d_in[1];
    const int*   argm   = (const int*)d_in[2];
    const float* w1d    = (const float*)d_in[3];
    const float* b1d    = (const float*)d_in[4];
    const float* w2d    = (const float*)d_in[5];
    const float* b2d    = (const float*)d_in[6];
    const float* wh     = (const float*)d_in[7];
    const float* bh     = (const float*)d_in[8];
    const float* wp     = (const float*)d_in[9];
    const float* bp     = (const float*)d_in[10];

    float* out_pos    = (float*)d_out;                       // [N,K]
    float* out_struct = out_pos + (size_t)N_ROWS * KNN;      // [N,DOUT]

    float*          XBp  = (float*)d_ws;                                  // [N,128] f32
    __hip_bfloat16* XA16 = (__hip_bfloat16*)(XBp + (size_t)N_ROWS * DOUT);// [N,128] bf16
    float*          WTp  = (float*)((char*)XA16 + (size_t)N_ROWS * DOUT * 2); // 32768 f32

    pack_wt<<<128, 256, 0, stream>>>(wh, WTp);
    gemm_xaxb<<<N_ROWS / 16, 256, 0, stream>>>(data_x, WTp, bh, XA16, XBp);
    fused_main<<<N_ROWS / 4, 256, 0, stream>>>(dists, argm, w1d, b1d, w2d, b2d,
                                               wp, bp, XA16, XBp, out_pos, out_struct);
}